// Round 5
// baseline (413.840 us; speedup 1.0000x reference)
//
#include <hip/hip_runtime.h>
#include <stdint.h>

typedef float    f32x2 __attribute__((ext_vector_type(2)));
typedef float    f32x4 __attribute__((ext_vector_type(4)));
typedef _Float16 f16x8 __attribute__((ext_vector_type(8)));
typedef unsigned int u32x4 __attribute__((ext_vector_type(4)));

#define NN     4096
#define KTOT   12288     // 3*4096 stacked k-rows
#define CDIM   384       // B*F_OUT*T = 2*16*12
#define BN     64
#define BK     32
#define TSTEPS 384       // KTOT / BK

// ---------------------------------------------------------------------------
// Kernel 1: z builder.  z[c][m'] (fp16), c = b*192 + o*12 + t, m' = k*4096+m
// (validated in round 2; modeled ~3-5 us, not the bottleneck)
// ---------------------------------------------------------------------------
__global__ __launch_bounds__(256) void zbuild_kernel(
    const float* __restrict__ x,      // (2,4096,16,12)
    const float* __restrict__ xj,     // (3,3)  [j][k]
    const float* __restrict__ gamma,  // (3,16,16) [j][f][o]
    _Float16* __restrict__ zws)       // (384, 12288)
{
  __shared__ float xs[32 * 193];
  __shared__ float lhs[768];       // [k][f][o]
  const int tid = threadIdx.x;
  const int b   = blockIdx.x & 1;
  const int m0  = (blockIdx.x >> 1) << 5;

  for (int e = tid; e < 768; e += 256) {
    const int k = e >> 8, fo = e & 255;
    float s = 0.f;
#pragma unroll
    for (int j = 0; j < 3; ++j) s += gamma[j * 256 + fo] * xj[j * 3 + k];
    lhs[e] = s;
  }
  const float* xsrc = x + (size_t)(b * 4096 + m0) * 192;
  for (int q = tid; q < 1536; q += 256) {
    const int fl  = q << 2;
    const int ml  = fl / 192;
    const int off = fl - ml * 192;
    const f32x4 v = *(const f32x4*)(xsrc + fl);
#pragma unroll
    for (int r = 0; r < 4; ++r) xs[ml * 193 + off + r] = v[r];
  }
  __syncthreads();

  for (int slot = tid; slot < 512; slot += 256) {
    const int ml = slot & 31, o = slot >> 5;
    float acc[3][12];
#pragma unroll
    for (int k = 0; k < 3; ++k)
#pragma unroll
      for (int t = 0; t < 12; ++t) acc[k][t] = 0.f;

#pragma unroll
    for (int f = 0; f < 16; ++f) {
      float xv[12];
#pragma unroll
      for (int t = 0; t < 12; ++t) xv[t] = xs[ml * 193 + f * 12 + t];
#pragma unroll
      for (int k = 0; k < 3; ++k) {
        const float lf = lhs[k * 256 + f * 16 + o];
#pragma unroll
        for (int t = 0; t < 12; ++t) acc[k][t] += xv[t] * lf;
      }
    }
    const int mg = m0 + ml;
    const int cb = b * 192 + o * 12;
#pragma unroll
    for (int k = 0; k < 3; ++k)
#pragma unroll
      for (int t = 0; t < 12; ++t)
        zws[(size_t)(cb + t) * KTOT + k * 4096 + mg] = (_Float16)acc[k][t];
  }
}

// ---------------------------------------------------------------------------
// Kernel 2: GEMM  OutT[c][n] = sum_m' z[c][m'] * cheb[m'][n]   (fp16 MFMA)
// v3: A (z) is NOT staged in LDS. Wave w owns c-rows [w*48, w*48+48) only, so
//     A-fragments load straight from global z (per-XCD L2-resident panel)
//     into VGPRs in MFMA layout: lane reads z[c = w*48+mi*16+l15]
//     [k-chunk l4*8..+8] = one 16B load. LDS = Bs only (8 KB) -> with
//     __launch_bounds__(512,4) (VGPR cap 128), 2 blocks/CU co-resident:
//     block #2's MFMAs cover block #1's barrier drain (m114 mechanism) that
//     the round-2 1-block/CU config exposed serially every step.
// block tile: 384c x 64n, BK=32, 512 thr (8 waves x wave-tile 48c x 64n),
// grid = 64 n-blocks x S;  by = blockIdx % 8 == XCD id -> z panel L2-local.
// Bs [n][m-pair] u32-packed, 16B-block XOR swizzle blk ^= (n>>2)&3.
// Per-CU step budget: HBM cheb ~1600 clk >> LDS ~350 clk, MFMA ~233 clk ->
// HBM-streaming-bound by design.
// ---------------------------------------------------------------------------
__global__ __launch_bounds__(512, 4) void gemm_kernel(
    const float* __restrict__ cheb,     // (12288, 4096)
    const _Float16* __restrict__ zws,   // (384, 12288)
    float* __restrict__ partials,       // (S, 384, 4096)
    int S, int spb)
{
  __shared__ unsigned int Bs[2][BN * BK / 2];   // 4 KB per buffer

  const int tid  = threadIdx.x;
  const int by   = blockIdx.x % S;     // k-chunk (== XCD id when S==8)
  const int bx   = blockIdx.x / S;     // n-block
  const int lane = tid & 63, wid = tid >> 6;
  const int l15  = lane & 15, l4 = lane >> 4;
  const int nbase = bx * BN;
  const int step0 = by * spb;
  int nsteps = TSTEPS - step0;
  if (nsteps > spb) nsteps = spb;
  if (nsteps < 0) nsteps = 0;

  f32x4 acc[3][4];
#pragma unroll
  for (int mi = 0; mi < 3; ++mi)
#pragma unroll
    for (int ni = 0; ni < 4; ++ni) acc[mi][ni] = (f32x4)(0.f);

  // --- B staging: 512 thr cover 32m x 64n fp32; thread: m-pair rr, cols nn,nn+1
  const int rr = tid >> 5;            // 0..15
  const int nn = (tid & 31) << 1;     // 0,2,..,62
  f32x2 b0, b1;
  auto LOADB = [&](int t) {
    const float* base = cheb + (size_t)(step0 + t) * BK * NN + nbase + nn;
    b0 = *(const f32x2*)(base + (size_t)(2 * rr)     * NN);
    b1 = *(const f32x2*)(base + (size_t)(2 * rr + 1) * NN);
  };
  auto WRITEB = [&](int buf) {
#pragma unroll
    for (int d = 0; d < 2; ++d) {
      const int n = nn + d;
      const _Float16 h0 = (_Float16)b0[d], h1 = (_Float16)b1[d];
      const uint32_t w = (uint32_t)__builtin_bit_cast(unsigned short, h0) |
                         ((uint32_t)__builtin_bit_cast(unsigned short, h1) << 16);
      const int blk = (n * 4 + (rr >> 2)) ^ ((n >> 2) & 3);
      Bs[buf][blk * 4 + (rr & 3)] = w;
    }
  };

  // --- A fragments direct from global z (L2): c = wid*48 + mi*16 + l15
  const char* abase = (const char*)zws +
      (size_t)(wid * 48 + l15) * (KTOT * 2) + (size_t)l4 * 16;
  auto LOADA = [&](int t, u32x4* ar) {
    const size_t kb = (size_t)(step0 + t) * (BK * 2);
#pragma unroll
    for (int mi = 0; mi < 3; ++mi)
      ar[mi] = *(const u32x4*)(abase + (size_t)mi * 16 * (KTOT * 2) + kb);
  };

  auto STEP = [&](int t, u32x4* arCur, u32x4* arNxt, int cur) {
    const bool pf = (t + 1 < nsteps);
    if (pf) LOADB(t + 1);                       // issue HBM loads first
    f16x8 bf[4];
#pragma unroll
    for (int ni = 0; ni < 4; ++ni) {
      const int n   = ni * 16 + l15;
      const int blk = (n * 4 + l4) ^ ((n >> 2) & 3);
      bf[ni] = *(const f16x8*)&Bs[cur][blk * 4];   // ds_read_b128
    }
    if (pf) LOADA(t + 1, arNxt);                // prefetch next A frags (L2)
#pragma unroll
    for (int mi = 0; mi < 3; ++mi) {
      const f16x8 af = __builtin_bit_cast(f16x8, arCur[mi]);
#pragma unroll
      for (int ni = 0; ni < 4; ++ni)
        acc[mi][ni] = __builtin_amdgcn_mfma_f32_16x16x32_f16(
            af, bf[ni], acc[mi][ni], 0, 0, 0);
    }
    if (pf) WRITEB(cur ^ 1);                    // waits only B loads (vmcnt)
    __syncthreads();
  };

  u32x4 arA[3], arB[3];
  if (nsteps > 0) {
    LOADB(0); WRITEB(0); LOADA(0, arA);
    __syncthreads();
    int t = 0;
    for (; t + 1 < nsteps; t += 2) {            // 2-step bodies: static A-reg swap
      STEP(t,     arA, arB, t & 1);
      STEP(t + 1, arB, arA, (t + 1) & 1);
    }
    if (t < nsteps) STEP(t, arA, arB, t & 1);
  }

  // epilogue: partials[by][c][n]  (C/D frag: col=lane&15, row=(lane>>4)*4+r)
  float* pb = partials + (size_t)by * ((size_t)CDIM * NN);
#pragma unroll
  for (int mi = 0; mi < 3; ++mi) {
    const int c0 = wid * 48 + mi * 16 + l4 * 4;
#pragma unroll
    for (int ni = 0; ni < 4; ++ni) {
      const int n = nbase + ni * 16 + l15;
#pragma unroll
      for (int r = 0; r < 4; ++r)
        pb[(size_t)(c0 + r) * NN + n] = acc[mi][ni][r];
    }
  }
}

// ---------------------------------------------------------------------------
// Kernel 3: sum S partial slabs, 0.5*relu, transpose c<->n via LDS,
// write out[b][n][o][t] coalesced.  (validated in round 2)
// ---------------------------------------------------------------------------
__global__ __launch_bounds__(256) void reduce_kernel(
    const float* __restrict__ partials, float* __restrict__ out, int S)
{
  __shared__ float T[192 * 33];
  const int tid = threadIdx.x;
  const int n0  = blockIdx.x * 32;
  const int cb  = blockIdx.y;

  for (int i = tid; i < 6144; i += 256) {
    const int c_l = i >> 5, n_l = i & 31;
    const float* p = partials + (size_t)(cb * 192 + c_l) * NN + n0 + n_l;
    float s = 0.f;
    for (int ss = 0; ss < S; ++ss) s += p[(size_t)ss * ((size_t)CDIM * NN)];
    T[c_l * 33 + n_l] = s;
  }
  __syncthreads();
  for (int j = tid; j < 6144; j += 256) {
    const int n_l = j / 192, ot = j - n_l * 192;
    const float v = 0.5f * T[ot * 33 + n_l];   // 2/(K+1) = 0.5
    out[(size_t)(cb * 4096 + n0 + n_l) * 192 + ot] = v > 0.f ? v : 0.f;
  }
}

// ---------------------------------------------------------------------------
extern "C" void kernel_launch(void* const* d_in, const int* in_sizes, int n_in,
                              void* d_out, int out_size, void* d_ws, size_t ws_size,
                              hipStream_t stream) {
  (void)in_sizes; (void)n_in; (void)out_size;
  const float* x     = (const float*)d_in[0];
  const float* cheb  = (const float*)d_in[1];
  const float* xj    = (const float*)d_in[2];
  const float* gamma = (const float*)d_in[3];
  float* out = (float*)d_out;

  const long long zbytes = (long long)CDIM * KTOT * 2;   // 9,437,184
  const long long pslab  = (long long)CDIM * NN * 4;     // 6,291,456
  int S = 8;
  const long long avail = (long long)ws_size - zbytes;
  if (avail < 8 * pslab) {
    S = (int)(avail / pslab);
    if (S < 1) S = 1;
    if (S > 8) S = 8;
  }
  const int spb = (TSTEPS + S - 1) / S;

  _Float16* zws   = (_Float16*)d_ws;
  float* partials = (float*)((char*)d_ws + zbytes);

  zbuild_kernel<<<256, 256, 0, stream>>>(x, xj, gamma, zws);
  gemm_kernel<<<(NN / BN) * S, 512, 0, stream>>>(cheb, zws, partials, S, spb);
  reduce_kernel<<<dim3(128, 2), 256, 0, stream>>>(partials, out, S);
}

// Round 6
// 411.572 us; speedup vs baseline: 1.0055x; 1.0055x over previous
//
#include <hip/hip_runtime.h>
#include <stdint.h>

typedef float    f32x2 __attribute__((ext_vector_type(2)));
typedef float    f32x4 __attribute__((ext_vector_type(4)));
typedef _Float16 f16x8 __attribute__((ext_vector_type(8)));
typedef unsigned int u32x4 __attribute__((ext_vector_type(4)));

#define NN     4096
#define KTOT   12288     // 3*4096 stacked k-rows
#define CDIM   384       // B*F_OUT*T = 2*16*12
#define BN     64
#define BK     32
#define TSTEPS 384       // KTOT / BK

// ---------------------------------------------------------------------------
// Kernel 1: z builder.  z[c][m'] (fp16), c = b*192 + o*12 + t, m' = k*4096+m
// (validated rounds 2/5; not the bottleneck)
// ---------------------------------------------------------------------------
__global__ __launch_bounds__(256) void zbuild_kernel(
    const float* __restrict__ x,      // (2,4096,16,12)
    const float* __restrict__ xj,     // (3,3)  [j][k]
    const float* __restrict__ gamma,  // (3,16,16) [j][f][o]
    _Float16* __restrict__ zws)       // (384, 12288)
{
  __shared__ float xs[32 * 193];
  __shared__ float lhs[768];       // [k][f][o]
  const int tid = threadIdx.x;
  const int b   = blockIdx.x & 1;
  const int m0  = (blockIdx.x >> 1) << 5;

  for (int e = tid; e < 768; e += 256) {
    const int k = e >> 8, fo = e & 255;
    float s = 0.f;
#pragma unroll
    for (int j = 0; j < 3; ++j) s += gamma[j * 256 + fo] * xj[j * 3 + k];
    lhs[e] = s;
  }
  const float* xsrc = x + (size_t)(b * 4096 + m0) * 192;
  for (int q = tid; q < 1536; q += 256) {
    const int fl  = q << 2;
    const int ml  = fl / 192;
    const int off = fl - ml * 192;
    const f32x4 v = *(const f32x4*)(xsrc + fl);
#pragma unroll
    for (int r = 0; r < 4; ++r) xs[ml * 193 + off + r] = v[r];
  }
  __syncthreads();

  for (int slot = tid; slot < 512; slot += 256) {
    const int ml = slot & 31, o = slot >> 5;
    float acc[3][12];
#pragma unroll
    for (int k = 0; k < 3; ++k)
#pragma unroll
      for (int t = 0; t < 12; ++t) acc[k][t] = 0.f;

#pragma unroll
    for (int f = 0; f < 16; ++f) {
      float xv[12];
#pragma unroll
      for (int t = 0; t < 12; ++t) xv[t] = xs[ml * 193 + f * 12 + t];
#pragma unroll
      for (int k = 0; k < 3; ++k) {
        const float lf = lhs[k * 256 + f * 16 + o];
#pragma unroll
        for (int t = 0; t < 12; ++t) acc[k][t] += xv[t] * lf;
      }
    }
    const int mg = m0 + ml;
    const int cb = b * 192 + o * 12;
#pragma unroll
    for (int k = 0; k < 3; ++k)
#pragma unroll
      for (int t = 0; t < 12; ++t)
        zws[(size_t)(cb + t) * KTOT + k * 4096 + mg] = (_Float16)acc[k][t];
  }
}

// ---------------------------------------------------------------------------
// Kernel 2: GEMM  OutT[c][n] = sum_m' z[c][m'] * cheb[m'][n]   (fp16 MFMA)
// v4 changes vs v5-bench (which was latency-bound: MfmaUtil 10%, hbm 14%):
//  (1) RAW barrier (lgkmcnt(0) + s_barrier builtin) instead of __syncthreads:
//      __syncthreads emits s_waitcnt vmcnt(0) -> drained the load queue every
//      step, exposing full HBM latency per step (the measured ~3700 cyc/step).
//      With the raw barrier, global loads stay in flight across steps and the
//      compiler's dependency-counted vmcnt waits only what's needed (T3/T4).
//  (2) B-prefetch 2-deep: LOADB(t+2) at step t, WRITEB(t+1) from the set
//      loaded at t-1 (~1.5-step latency window). A issued BEFORE B so the
//      in-order vmcnt wait on A(t) doesn't force B(t+1) early.
//  (3) swizzle blk = (n*4+q) ^ ((n>>1)&7): write conflicts 8->4-way
//      (old (n>>2)&3 ignored nn's low bit; bank hit only 8 banks 8-way).
// ---------------------------------------------------------------------------
__global__ __launch_bounds__(512, 4) void gemm_kernel(
    const float* __restrict__ cheb,     // (12288, 4096)
    const _Float16* __restrict__ zws,   // (384, 12288)
    float* __restrict__ partials,       // (S, 384, 4096)
    int S, int spb)
{
  __shared__ unsigned int Bs[2][BN * BK / 2];   // 4 KB per buffer

  const int tid  = threadIdx.x;
  const int by   = blockIdx.x % S;     // k-chunk (== XCD id when S==8)
  const int bx   = blockIdx.x / S;     // n-block
  const int lane = tid & 63, wid = tid >> 6;
  const int l15  = lane & 15, l4 = lane >> 4;
  const int nbase = bx * BN;
  const int step0 = by * spb;
  int nsteps = TSTEPS - step0;
  if (nsteps > spb) nsteps = spb;
  if (nsteps < 0) nsteps = 0;

  f32x4 acc[3][4];
#pragma unroll
  for (int mi = 0; mi < 3; ++mi)
#pragma unroll
    for (int ni = 0; ni < 4; ++ni) acc[mi][ni] = (f32x4)(0.f);

  // --- B staging: 512 thr cover 32m x 64n fp32; thread: m-pair rr, cols nn,nn+1
  const int rr = tid >> 5;            // 0..15
  const int nn = (tid & 31) << 1;     // 0,2,..,62
  auto LOADB = [&](int t, f32x2* br) {
    const float* base = cheb + (size_t)(step0 + t) * BK * NN + nbase + nn;
    br[0] = *(const f32x2*)(base + (size_t)(2 * rr)     * NN);
    br[1] = *(const f32x2*)(base + (size_t)(2 * rr + 1) * NN);
  };
  auto WRITEB = [&](int buf, f32x2* br) {
#pragma unroll
    for (int d = 0; d < 2; ++d) {
      const int n = nn + d;
      const _Float16 h0 = (_Float16)br[0][d];   // k = 2*rr
      const _Float16 h1 = (_Float16)br[1][d];   // k = 2*rr+1
      const uint32_t w = (uint32_t)__builtin_bit_cast(unsigned short, h0) |
                         ((uint32_t)__builtin_bit_cast(unsigned short, h1) << 16);
      const int blk = (n * 4 + (rr >> 2)) ^ ((n >> 1) & 7);
      Bs[buf][blk * 4 + (rr & 3)] = w;
    }
  };

  // --- A fragments direct from global z (L2): c = wid*48 + mi*16 + l15
  const char* abase = (const char*)zws +
      (size_t)(wid * 48 + l15) * (KTOT * 2) + (size_t)l4 * 16;
  auto LOADA = [&](int t, u32x4* ar) {
    const size_t kb = (size_t)(step0 + t) * (BK * 2);
#pragma unroll
    for (int mi = 0; mi < 3; ++mi)
      ar[mi] = *(const u32x4*)(abase + (size_t)mi * 16 * (KTOT * 2) + kb);
  };

  // step t: issue A(t+1), B(t+2); ds_read Bs[t&1]; MFMA with A(t);
  //         WRITEB(t+1) (regs from step t-1; vmcnt already satisfied by
  //         the in-order A(t) wait); raw barrier (NO vmcnt drain).
  auto STEP = [&](int t, int cur, f32x2* bL, f32x2* bW, u32x4* arC, u32x4* arN) {
    if (t + 1 < nsteps) LOADA(t + 1, arN);
    if (t + 2 < nsteps) LOADB(t + 2, bL);
    f16x8 bf[4];
#pragma unroll
    for (int ni = 0; ni < 4; ++ni) {
      const int n   = ni * 16 + l15;
      const int blk = (n * 4 + l4) ^ ((n >> 1) & 7);
      bf[ni] = *(const f16x8*)&Bs[cur][blk * 4];   // ds_read_b128
    }
#pragma unroll
    for (int mi = 0; mi < 3; ++mi) {
      const f16x8 af = __builtin_bit_cast(f16x8, arC[mi]);
#pragma unroll
      for (int ni = 0; ni < 4; ++ni)
        acc[mi][ni] = __builtin_amdgcn_mfma_f32_16x16x32_f16(
            af, bf[ni], acc[mi][ni], 0, 0, 0);
    }
    if (t + 1 < nsteps) WRITEB(cur ^ 1, bW);
    asm volatile("s_waitcnt lgkmcnt(0)" ::: "memory");
    __builtin_amdgcn_s_barrier();
  };

  f32x2 bs0[2], bs1[2];
  u32x4 arA[3], arB[3];
  if (nsteps > 0) {
    LOADA(0, arA);
    LOADB(0, bs0);
    if (nsteps > 1) LOADB(1, bs1);
    WRITEB(0, bs0);
    asm volatile("s_waitcnt lgkmcnt(0)" ::: "memory");
    __builtin_amdgcn_s_barrier();
    int t = 0;
    for (; t + 1 < nsteps; t += 2) {   // unroll-2: static reg-set rotation
      STEP(t,     0, bs0, bs1, arA, arB);   // load(t+2)->bs0, flush(t+1)<-bs1
      STEP(t + 1, 1, bs1, bs0, arB, arA);
    }
    if (t < nsteps) STEP(t, 0, bs0, bs1, arA, arB);  // t even at loop exit
  }

  // epilogue: partials[by][c][n]  (C/D frag: col=lane&15, row=(lane>>4)*4+r)
  float* pb = partials + (size_t)by * ((size_t)CDIM * NN);
#pragma unroll
  for (int mi = 0; mi < 3; ++mi) {
    const int c0 = wid * 48 + mi * 16 + l4 * 4;
#pragma unroll
    for (int ni = 0; ni < 4; ++ni) {
      const int n = nbase + ni * 16 + l15;
#pragma unroll
      for (int r = 0; r < 4; ++r)
        pb[(size_t)(c0 + r) * NN + n] = acc[mi][ni][r];
    }
  }
}

// ---------------------------------------------------------------------------
// Kernel 3: sum S partial slabs, 0.5*relu, transpose c<->n via LDS,
// write out[b][n][o][t] coalesced.  (validated)
// ---------------------------------------------------------------------------
__global__ __launch_bounds__(256) void reduce_kernel(
    const float* __restrict__ partials, float* __restrict__ out, int S)
{
  __shared__ float T[192 * 33];
  const int tid = threadIdx.x;
  const int n0  = blockIdx.x * 32;
  const int cb  = blockIdx.y;

  for (int i = tid; i < 6144; i += 256) {
    const int c_l = i >> 5, n_l = i & 31;
    const float* p = partials + (size_t)(cb * 192 + c_l) * NN + n0 + n_l;
    float s = 0.f;
    for (int ss = 0; ss < S; ++ss) s += p[(size_t)ss * ((size_t)CDIM * NN)];
    T[c_l * 33 + n_l] = s;
  }
  __syncthreads();
  for (int j = tid; j < 6144; j += 256) {
    const int n_l = j / 192, ot = j - n_l * 192;
    const float v = 0.5f * T[ot * 33 + n_l];   // 2/(K+1) = 0.5
    out[(size_t)(cb * 4096 + n0 + n_l) * 192 + ot] = v > 0.f ? v : 0.f;
  }
}

// ---------------------------------------------------------------------------
extern "C" void kernel_launch(void* const* d_in, const int* in_sizes, int n_in,
                              void* d_out, int out_size, void* d_ws, size_t ws_size,
                              hipStream_t stream) {
  (void)in_sizes; (void)n_in; (void)out_size;
  const float* x     = (const float*)d_in[0];
  const float* cheb  = (const float*)d_in[1];
  const float* xj    = (const float*)d_in[2];
  const float* gamma = (const float*)d_in[3];
  float* out = (float*)d_out;

  const long long zbytes = (long long)CDIM * KTOT * 2;   // 9,437,184
  const long long pslab  = (long long)CDIM * NN * 4;     // 6,291,456
  int S = 8;
  const long long avail = (long long)ws_size - zbytes;
  if (avail < 8 * pslab) {
    S = (int)(avail / pslab);
    if (S < 1) S = 1;
    if (S > 8) S = 8;
  }
  const int spb = (TSTEPS + S - 1) / S;

  _Float16* zws   = (_Float16*)d_ws;
  float* partials = (float*)((char*)d_ws + zbytes);

  zbuild_kernel<<<256, 256, 0, stream>>>(x, xj, gamma, zws);
  gemm_kernel<<<(NN / BN) * S, 512, 0, stream>>>(cheb, zws, partials, S, spb);
  reduce_kernel<<<dim3(128, 2), 256, 0, stream>>>(partials, out, S);
}

// Round 8
// 411.524 us; speedup vs baseline: 1.0056x; 1.0001x over previous
//
#include <hip/hip_runtime.h>
#include <stdint.h>

typedef float    f32x2 __attribute__((ext_vector_type(2)));
typedef float    f32x4 __attribute__((ext_vector_type(4)));
typedef _Float16 f16x8 __attribute__((ext_vector_type(8)));
typedef unsigned int u32x4 __attribute__((ext_vector_type(4)));

#define NN     4096
#define KTOT   12288     // 3*4096 stacked k-rows
#define CDIM   384       // B*F_OUT*T = 2*16*12
#define BN     64
#define BK     32
#define TSTEPS 384       // KTOT / BK

// ---------------------------------------------------------------------------
// Kernel 1: z builder (validated rounds 2/5/6; not the bottleneck)
// ---------------------------------------------------------------------------
__global__ __launch_bounds__(256) void zbuild_kernel(
    const float* __restrict__ x,      // (2,4096,16,12)
    const float* __restrict__ xj,     // (3,3)  [j][k]
    const float* __restrict__ gamma,  // (3,16,16) [j][f][o]
    _Float16* __restrict__ zws)       // (384, 12288)
{
  __shared__ float xs[32 * 193];
  __shared__ float lhs[768];       // [k][f][o]
  const int tid = threadIdx.x;
  const int b   = blockIdx.x & 1;
  const int m0  = (blockIdx.x >> 1) << 5;

  for (int e = tid; e < 768; e += 256) {
    const int k = e >> 8, fo = e & 255;
    float s = 0.f;
#pragma unroll
    for (int j = 0; j < 3; ++j) s += gamma[j * 256 + fo] * xj[j * 3 + k];
    lhs[e] = s;
  }
  const float* xsrc = x + (size_t)(b * 4096 + m0) * 192;
  for (int q = tid; q < 1536; q += 256) {
    const int fl  = q << 2;
    const int ml  = fl / 192;
    const int off = fl - ml * 192;
    const f32x4 v = *(const f32x4*)(xsrc + fl);
#pragma unroll
    for (int r = 0; r < 4; ++r) xs[ml * 193 + off + r] = v[r];
  }
  __syncthreads();

  for (int slot = tid; slot < 512; slot += 256) {
    const int ml = slot & 31, o = slot >> 5;
    float acc[3][12];
#pragma unroll
    for (int k = 0; k < 3; ++k)
#pragma unroll
      for (int t = 0; t < 12; ++t) acc[k][t] = 0.f;

#pragma unroll
    for (int f = 0; f < 16; ++f) {
      float xv[12];
#pragma unroll
      for (int t = 0; t < 12; ++t) xv[t] = xs[ml * 193 + f * 12 + t];
#pragma unroll
      for (int k = 0; k < 3; ++k) {
        const float lf = lhs[k * 256 + f * 16 + o];
#pragma unroll
        for (int t = 0; t < 12; ++t) acc[k][t] += xv[t] * lf;
      }
    }
    const int mg = m0 + ml;
    const int cb = b * 192 + o * 12;
#pragma unroll
    for (int k = 0; k < 3; ++k)
#pragma unroll
      for (int t = 0; t < 12; ++t)
        zws[(size_t)(cb + t) * KTOT + k * 4096 + mg] = (_Float16)acc[k][t];
  }
}

// ---------------------------------------------------------------------------
// Kernel 2: GEMM  OutT[c][n] = sum_m' z[c][m'] * cheb[m'][n]   (fp16 MFMA)
// v5: deep pipeline. v2/v3/v4 all ~148us with EVERYTHING idle (Mfma 10%,
// VALU 7%, hbm 14%): every structure waited on loads issued <=1 step before
// use -> each step's critical path ate a full memory latency and both
// co-resident blocks stalled at the same point. v5 buys depth with regs:
//   B: 4 named reg sets, LOADB(t+4) at phase t; LDS-write at t from the
//      3-phase-old set (vmcnt wait ~free); LDS double-buffer, write t+1's buf.
//   A: 2 named reg sets, LOADA(t+2) issued AFTER phase t's MFMAs (set reuse);
//      MFMA(t) waits a load issued 2 phases (~1300cyc) ago (vmcnt(11)).
//   4-phase unrolled loop, all reg sets named scalars via macros (no
//   runtime-indexed arrays -> no scratch). Raw lgkmcnt(0)+s_barrier (no
//   vmcnt drain). ds_writes before MFMA so lgkm drains under compute.
// ---------------------------------------------------------------------------
#define LOADA_(T, R0, R1, R2) do {                                          \
    const size_t kb_ = (size_t)(step0 + (T)) * (BK * 2);                    \
    R0 = *(const u32x4*)(abase + kb_);                                      \
    R1 = *(const u32x4*)(abase + (size_t)16 * (KTOT * 2) + kb_);            \
    R2 = *(const u32x4*)(abase + (size_t)32 * (KTOT * 2) + kb_);            \
  } while (0)

#define LOADB_(T, QA, QB) do {                                              \
    const float* base_ = cheb + (size_t)(step0 + (T)) * BK * NN + nbase + nn; \
    QA = *(const f32x2*)(base_ + (size_t)(2 * rr) * NN);                    \
    QB = *(const f32x2*)(base_ + (size_t)(2 * rr + 1) * NN);                \
  } while (0)

#define WRITEB_(BUF, QA, QB) do {                                           \
    _Float16 h0_, h1_; uint32_t w_;                                         \
    h0_ = (_Float16)QA[0]; h1_ = (_Float16)QB[0];                           \
    w_ = (uint32_t)__builtin_bit_cast(unsigned short, h0_) |                \
         ((uint32_t)__builtin_bit_cast(unsigned short, h1_) << 16);         \
    Bs[BUF][(((nn) * 4 + (rr >> 2)) ^ (((nn) >> 1) & 7)) * 4 + (rr & 3)] = w_; \
    h0_ = (_Float16)QA[1]; h1_ = (_Float16)QB[1];                           \
    w_ = (uint32_t)__builtin_bit_cast(unsigned short, h0_) |                \
         ((uint32_t)__builtin_bit_cast(unsigned short, h1_) << 16);         \
    Bs[BUF][(((nn + 1) * 4 + (rr >> 2)) ^ (((nn + 1) >> 1) & 7)) * 4 + (rr & 3)] = w_; \
  } while (0)

#define MFMA_ROW_(MI, AREG)                                                 \
  { const f16x8 af_ = __builtin_bit_cast(f16x8, AREG);                      \
    acc[MI][0] = __builtin_amdgcn_mfma_f32_16x16x32_f16(af_, bf0_, acc[MI][0], 0, 0, 0); \
    acc[MI][1] = __builtin_amdgcn_mfma_f32_16x16x32_f16(af_, bf1_, acc[MI][1], 0, 0, 0); \
    acc[MI][2] = __builtin_amdgcn_mfma_f32_16x16x32_f16(af_, bf2_, acc[MI][2], 0, 0, 0); \
    acc[MI][3] = __builtin_amdgcn_mfma_f32_16x16x32_f16(af_, bf3_, acc[MI][3], 0, 0, 0); }

#define PHASE_(T, A0_, A1_, A2_, QWA, QWB, QLA, QLB) do {                   \
    const int t_ = (T);                                                     \
    const int cur_ = t_ & 1;                                                \
    f16x8 bf0_, bf1_, bf2_, bf3_;                                           \
    { const int n_ = l15;      bf0_ = *(const f16x8*)&Bs[cur_][((n_ * 4 + l4) ^ ((n_ >> 1) & 7)) * 4]; } \
    { const int n_ = 16 + l15; bf1_ = *(const f16x8*)&Bs[cur_][((n_ * 4 + l4) ^ ((n_ >> 1) & 7)) * 4]; } \
    { const int n_ = 32 + l15; bf2_ = *(const f16x8*)&Bs[cur_][((n_ * 4 + l4) ^ ((n_ >> 1) & 7)) * 4]; } \
    { const int n_ = 48 + l15; bf3_ = *(const f16x8*)&Bs[cur_][((n_ * 4 + l4) ^ ((n_ >> 1) & 7)) * 4]; } \
    if (t_ + 1 < nsteps) WRITEB_((t_ + 1) & 1, QWA, QWB);                   \
    MFMA_ROW_(0, A0_)                                                       \
    MFMA_ROW_(1, A1_)                                                       \
    MFMA_ROW_(2, A2_)                                                       \
    if (t_ + 2 < nsteps) LOADA_(t_ + 2, A0_, A1_, A2_);                     \
    if (t_ + 4 < nsteps) LOADB_(t_ + 4, QLA, QLB);                          \
    asm volatile("s_waitcnt lgkmcnt(0)" ::: "memory");                      \
    __builtin_amdgcn_s_barrier();                                           \
  } while (0)

__global__ __launch_bounds__(512, 4) void gemm_kernel(
    const float* __restrict__ cheb,     // (12288, 4096)
    const _Float16* __restrict__ zws,   // (384, 12288)
    float* __restrict__ partials,       // (S, 384, 4096)
    int S, int spb)
{
  __shared__ unsigned int Bs[2][BN * BK / 2];   // 4 KB per buffer

  const int tid  = threadIdx.x;
  const int by   = blockIdx.x % S;     // k-chunk (== XCD id when S==8)
  const int bx   = blockIdx.x / S;     // n-block
  const int lane = tid & 63, wid = tid >> 6;
  const int l15  = lane & 15, l4 = lane >> 4;
  const int nbase = bx * BN;
  const int step0 = by * spb;
  int nsteps = TSTEPS - step0;
  if (nsteps > spb) nsteps = spb;
  if (nsteps < 0) nsteps = 0;

  f32x4 acc[3][4];
#pragma unroll
  for (int mi = 0; mi < 3; ++mi)
#pragma unroll
    for (int ni = 0; ni < 4; ++ni) acc[mi][ni] = (f32x4)(0.f);

  const int rr = tid >> 5;            // 0..15  (B staging m-pair)
  const int nn = (tid & 31) << 1;     // 0,2,..,62  (B staging col pair)

  // A fragments direct from global z (L2/L3): c = wid*48 + mi*16 + l15
  const char* abase = (const char*)zws +
      (size_t)(wid * 48 + l15) * (KTOT * 2) + (size_t)l4 * 16;

  u32x4 A00, A01, A02, A10, A11, A12;
  f32x2 q0a, q0b, q1a, q1b, q2a, q2b, q3a, q3b;

  if (nsteps > 0) {
    LOADA_(0, A00, A01, A02);
    if (nsteps > 1) LOADA_(1, A10, A11, A12);
    LOADB_(0, q0a, q0b);
    if (nsteps > 1) LOADB_(1, q1a, q1b);
    if (nsteps > 2) LOADB_(2, q2a, q2b);
    if (nsteps > 3) LOADB_(3, q3a, q3b);
    WRITEB_(0, q0a, q0b);
    asm volatile("s_waitcnt lgkmcnt(0)" ::: "memory");
    __builtin_amdgcn_s_barrier();
    for (int t = 0; t < nsteps; t += 4) {
      PHASE_(t + 0, A00, A01, A02, q1a, q1b, q0a, q0b);
      if (t + 1 < nsteps) PHASE_(t + 1, A10, A11, A12, q2a, q2b, q1a, q1b);
      if (t + 2 < nsteps) PHASE_(t + 2, A00, A01, A02, q3a, q3b, q2a, q2b);
      if (t + 3 < nsteps) PHASE_(t + 3, A10, A11, A12, q0a, q0b, q3a, q3b);
    }
  }

  // epilogue: partials[by][c][n]  (C/D frag: col=lane&15, row=(lane>>4)*4+r)
  float* pb = partials + (size_t)by * ((size_t)CDIM * NN);
#pragma unroll
  for (int mi = 0; mi < 3; ++mi) {
    const int c0 = wid * 48 + mi * 16 + l4 * 4;
#pragma unroll
    for (int ni = 0; ni < 4; ++ni) {
      const int n = nbase + ni * 16 + l15;
#pragma unroll
      for (int r = 0; r < 4; ++r)
        pb[(size_t)(c0 + r) * NN + n] = acc[mi][ni][r];
    }
  }
}

// ---------------------------------------------------------------------------
// Kernel 3: sum S partial slabs, 0.5*relu, transpose c<->n via LDS,
// write out[b][n][o][t] coalesced.  (validated)
// ---------------------------------------------------------------------------
__global__ __launch_bounds__(256) void reduce_kernel(
    const float* __restrict__ partials, float* __restrict__ out, int S)
{
  __shared__ float T[192 * 33];
  const int tid = threadIdx.x;
  const int n0  = blockIdx.x * 32;
  const int cb  = blockIdx.y;

  for (int i = tid; i < 6144; i += 256) {
    const int c_l = i >> 5, n_l = i & 31;
    const float* p = partials + (size_t)(cb * 192 + c_l) * NN + n0 + n_l;
    float s = 0.f;
    for (int ss = 0; ss < S; ++ss) s += p[(size_t)ss * ((size_t)CDIM * NN)];
    T[c_l * 33 + n_l] = s;
  }
  __syncthreads();
  for (int j = tid; j < 6144; j += 256) {
    const int n_l = j / 192, ot = j - n_l * 192;
    const float v = 0.5f * T[ot * 33 + n_l];   // 2/(K+1) = 0.5
    out[(size_t)(cb * 4096 + n0 + n_l) * 192 + ot] = v > 0.f ? v : 0.f;
  }
}

// ---------------------------------------------------------------------------
extern "C" void kernel_launch(void* const* d_in, const int* in_sizes, int n_in,
                              void* d_out, int out_size, void* d_ws, size_t ws_size,
                              hipStream_t stream) {
  (void)in_sizes; (void)n_in; (void)out_size;
  const float* x     = (const float*)d_in[0];
  const float* cheb  = (const float*)d_in[1];
  const float* xj    = (const float*)d_in[2];
  const float* gamma = (const float*)d_in[3];
  float* out = (float*)d_out;

  const long long zbytes = (long long)CDIM * KTOT * 2;   // 9,437,184
  const long long pslab  = (long long)CDIM * NN * 4;     // 6,291,456
  int S = 8;
  const long long avail = (long long)ws_size - zbytes;
  if (avail < 8 * pslab) {
    S = (int)(avail / pslab);
    if (S < 1) S = 1;
    if (S > 8) S = 8;
  }
  const int spb = (TSTEPS + S - 1) / S;

  _Float16* zws   = (_Float16*)d_ws;
  float* partials = (float*)((char*)d_ws + zbytes);

  zbuild_kernel<<<256, 256, 0, stream>>>(x, xj, gamma, zws);
  gemm_kernel<<<(NN / BN) * S, 512, 0, stream>>>(cheb, zws, partials, S, spb);
  reduce_kernel<<<dim3(128, 2), 256, 0, stream>>>(partials, out, S);
}